// Round 12
// baseline (929.760 us; speedup 1.0000x reference)
//
#include <hip/hip_runtime.h>
#include <cstdint>
#include <cstddef>

#define N_ROWS 131072   // B*T
#define T_LEN 2048
#define B_BATCH 64
#define H_DIM 128
#define GEMM_GRID 1024  // 128 rows per block
#define G_BATCH 16      // batches per rnn block
#define RNN_BLOCKS (B_BATCH / G_BATCH)
#define RWND 4          // rnn window (wx prefetch depth)
#define LOG2E 1.4426950408889634f

typedef _Float16 half2_t __attribute__((ext_vector_type(2)));
typedef _Float16 half8_t __attribute__((ext_vector_type(8)));
typedef float f32x4_t __attribute__((ext_vector_type(4)));
typedef int int2_t __attribute__((ext_vector_type(2)));

// permlaneN_swap butterfly sum: lane i ends with x[i] + x[i^N].
__device__ __forceinline__ float permlane16_sum(float x) {
  int i = __float_as_int(x);
  int2_t r = __builtin_amdgcn_permlane16_swap(i, i, false, false);
  return __int_as_float(r.x) + __int_as_float(r.y);
}
__device__ __forceinline__ float permlane32_sum(float x) {
  int i = __float_as_int(x);
  int2_t r = __builtin_amdgcn_permlane32_swap(i, i, false, false);
  return __int_as_float(r.x) + __int_as_float(r.y);
}

__device__ __forceinline__ float sigmoid2_fast(float spp) {
  // y = 1/(1 + 2^spp), spp already scaled by -log2e
  return __builtin_amdgcn_rcpf(1.0f + __builtin_amdgcn_exp2f(spp));
}

// ---------------------------------------------------------------------------
// Kernel 1: Wx = x @ W^T + fused BN column stats — MFMA (R10-verified).
// ---------------------------------------------------------------------------
__global__ __launch_bounds__(256) void gemm_bn_kernel(
    const float* __restrict__ x, const float* __restrict__ W,
    float* __restrict__ Wx, float* __restrict__ stats)
{
  const int tid  = threadIdx.x;
  const int lane = tid & 63;
  const int wv   = tid >> 6;        // wave 0..3
  const int l15  = lane & 15;
  const int kg   = lane >> 4;       // k-group 0..3
  const int r0   = blockIdx.x * 128;

  half8_t Bf[2][4];
#pragma unroll
  for (int n = 0; n < 2; ++n) {
    const int col = wv * 32 + n * 16 + l15;
    const float* wp = W + (size_t)col * H_DIM;
#pragma unroll
    for (int k = 0; k < 4; ++k) {
      const float* w8 = wp + k * 32 + kg * 8;
      half8_t b;
#pragma unroll
      for (int i = 0; i < 8; ++i) b[i] = (_Float16)w8[i];
      Bf[n][k] = b;
    }
  }

  __shared__ __align__(16) _Float16 xs[128 * 128];
  {
    const int row = tid >> 1;
    const int hf  = tid & 1;
    const float* xp = x + (size_t)(r0 + row) * H_DIM + hf * 64;
    const int swz = (row & 7) << 4;
    char* base = reinterpret_cast<char*>(xs) + row * 256;
#pragma unroll
    for (int c = 0; c < 8; ++c) {
      float4 v0 = *reinterpret_cast<const float4*>(xp + c * 8);
      float4 v1 = *reinterpret_cast<const float4*>(xp + c * 8 + 4);
      half8_t h;
      h[0] = (_Float16)v0.x; h[1] = (_Float16)v0.y;
      h[2] = (_Float16)v0.z; h[3] = (_Float16)v0.w;
      h[4] = (_Float16)v1.x; h[5] = (_Float16)v1.y;
      h[6] = (_Float16)v1.z; h[7] = (_Float16)v1.w;
      const int X = hf * 128 + c * 16;
      *reinterpret_cast<half8_t*>(base + (X ^ swz)) = h;
    }
  }
  __syncthreads();

  f32x4_t C[8][2];
#pragma unroll
  for (int m = 0; m < 8; ++m)
#pragma unroll
    for (int n = 0; n < 2; ++n)
      C[m][n] = (f32x4_t){0.f, 0.f, 0.f, 0.f};

#pragma unroll
  for (int m = 0; m < 8; ++m) {
    const int row = m * 16 + l15;
    const char* rbase = reinterpret_cast<const char*>(xs) + row * 256;
    const int swz = (row & 7) << 4;
#pragma unroll
    for (int k = 0; k < 4; ++k) {
      const int X = k * 64 + kg * 16;
      half8_t a = *reinterpret_cast<const half8_t*>(rbase + (X ^ swz));
      C[m][0] = __builtin_amdgcn_mfma_f32_16x16x32_f16(a, Bf[0][k], C[m][0], 0, 0, 0);
      C[m][1] = __builtin_amdgcn_mfma_f32_16x16x32_f16(a, Bf[1][k], C[m][1], 0, 0, 0);
    }
  }

  float sum0 = 0.f, sq0 = 0.f, sum1 = 0.f, sq1 = 0.f;
#pragma unroll
  for (int m = 0; m < 8; ++m) {
#pragma unroll
    for (int j = 0; j < 4; ++j) {
      const int row = r0 + m * 16 + kg * 4 + j;
      const float v0 = C[m][0][j];
      const float v1 = C[m][1][j];
      Wx[(size_t)row * H_DIM + wv * 32 + l15]      = v0;
      Wx[(size_t)row * H_DIM + wv * 32 + 16 + l15] = v1;
      sum0 += v0; sq0 = fmaf(v0, v0, sq0);
      sum1 += v1; sq1 = fmaf(v1, v1, sq1);
    }
  }
  float s0 = permlane32_sum(permlane16_sum(sum0));
  float q0 = permlane32_sum(permlane16_sum(sq0));
  float s1 = permlane32_sum(permlane16_sum(sum1));
  float q1 = permlane32_sum(permlane16_sum(sq1));
  if (lane < 16) {
    atomicAdd(&stats[wv * 32 + lane],              s0);
    atomicAdd(&stats[H_DIM + wv * 32 + lane],      q0);
    atomicAdd(&stats[wv * 32 + 16 + lane],         s1);
    atomicAdd(&stats[H_DIM + wv * 32 + 16 + lane], q1);
  }
}

// ---------------------------------------------------------------------------
// Kernel 2: fold BN stats into scale/shift
// ---------------------------------------------------------------------------
__global__ void bn_finalize_kernel(float* ws, const float* __restrict__ gamma,
                                   const float* __restrict__ beta)
{
  const int h = threadIdx.x;
  const float invN = 1.0f / (float)N_ROWS;
  float mean = ws[h] * invN;
  float e2   = ws[H_DIM + h] * invN;
  float var  = e2 - mean * mean;
  float scl  = gamma[h] * rsqrtf(var + 1e-5f);
  ws[2 * H_DIM + h] = scl;
  ws[3 * H_DIM + h] = beta[h] - mean * scl;
}

// ---------------------------------------------------------------------------
// Kernel 3: recurrence via MFMA. G=16 batches per block (4 blocks), 4 waves.
// y-state: 16x128 f16 tile, LDS ping-pong, XOR-swizzled (byte^=(row&7)<<4 on
// 16B chunks; row = batch). Per step per wave (owns 32 output cols = 2
// n-tiles): 4x ds_read_b128 A-frags (A row = batch = lane&15, k = H-dim) ->
// 2 chains of 4 chained mfma_f32_16x16x32_f16 with C SEEDED by pre-scaled
// wx (C-in = accumulator) -> no reduce stage; C holds full dots -> sigmoid
// (exp2 domain) on 8 outputs -> 8x ds_write_b16 into next buffer in A-layout
// (write byte = (col*2)^((row&7)<<4), same mapping as reads) + fire-and-
// forget global f32 stores. Sync: proven lgkmcnt(0)+s_barrier per step.
// Frag layouts HW-verified by the R10 GEMM (same intrinsic/constructions).
// ---------------------------------------------------------------------------
__global__ __launch_bounds__(256) void rnn_mfma_kernel(
    const float* __restrict__ V, float* __restrict__ out,
    const float* __restrict__ ws)
{
  const int tid  = threadIdx.x;
  const int lane = tid & 63;
  const int wv   = tid >> 6;        // wave 0..3
  const int n15  = lane & 15;       // B col within n-tile / A row (batch)
  const int kg   = lane >> 4;       // k-group 0..3

  const int col0 = wv * 32 + n15;   // n-tile 0
  const int col1 = col0 + 16;       // n-tile 1

  // B-frags: B[k][n] = Vs[col=n][k], Vs = -log2e * V as f16.
  half8_t Bf[2][4];
#pragma unroll
  for (int nt = 0; nt < 2; ++nt) {
    const int col = nt ? col1 : col0;
    const float* vp = V + (size_t)col * H_DIM;
#pragma unroll
    for (int ks = 0; ks < 4; ++ks) {
      const float* v8 = vp + ks * 32 + kg * 8;
      half8_t b;
#pragma unroll
      for (int i = 0; i < 8; ++i) b[i] = (_Float16)(-LOG2E * v8[i]);
      Bf[nt][ks] = b;
    }
  }
  float scl[2], shf[2];
  scl[0] = ws[2 * H_DIM + col0] * (-LOG2E);
  shf[0] = ws[3 * H_DIM + col0] * (-LOG2E);
  scl[1] = ws[2 * H_DIM + col1] * (-LOG2E);
  shf[1] = ws[3 * H_DIM + col1] * (-LOG2E);

  __shared__ __align__(16) _Float16 ylds[2 * G_BATCH * H_DIM];  // 8 KB
  float* outb = out + (size_t)blockIdx.x * G_BATCH * T_LEN * H_DIM;

  {  // zero both y buffers (y_0 = 0): 8192 B / 256 thr = 32 B each
    half8_t z = {};
    char* zb = reinterpret_cast<char*>(ylds) + tid * 32;
    *reinterpret_cast<half8_t*>(zb)      = z;
    *reinterpret_cast<half8_t*>(zb + 16) = z;
  }

  // wx window: wxp[u][nt][j] = -log2e*(wx_norm) for batch row kg*4+j, step u
  float wxp[RWND][2][4];
#pragma unroll
  for (int u = 0; u < RWND; ++u)
#pragma unroll
    for (int nt = 0; nt < 2; ++nt)
#pragma unroll
      for (int j = 0; j < 4; ++j) {
        const int col = nt ? col1 : col0;
        float r = outb[((size_t)(kg * 4 + j) * T_LEN + u) * H_DIM + col];
        wxp[u][nt][j] = fmaf(r, scl[nt], shf[nt]);
      }
  __syncthreads();

  const int rsw = (n15 & 7) << 4;   // A-read swizzle (row = n15)
  const char* ybase = reinterpret_cast<const char*>(ylds);
  char* ybase_w = reinterpret_cast<char*>(ylds);

  for (int w = 0; w < T_LEN; w += RWND) {
    const bool more = (w + RWND < T_LEN);
    float wxn[RWND][2][4];
    if (more) {  // raw prefetch; hides under ~4 steps of compute
#pragma unroll
      for (int u = 0; u < RWND; ++u)
#pragma unroll
        for (int nt = 0; nt < 2; ++nt)
#pragma unroll
          for (int j = 0; j < 4; ++j) {
            const int col = nt ? col1 : col0;
            wxn[u][nt][j] =
                outb[((size_t)(kg * 4 + j) * T_LEN + (w + RWND + u)) * H_DIM + col];
          }
    }

#pragma unroll
    for (int u = 0; u < RWND; ++u) {
      const int t = w + u;
      const int cur = t & 1;
      const char* rb = ybase + cur * 4096 + n15 * 256;
      half8_t a0 = *reinterpret_cast<const half8_t*>(rb + ((0 * 64 + kg * 16) ^ rsw));
      half8_t a1 = *reinterpret_cast<const half8_t*>(rb + ((1 * 64 + kg * 16) ^ rsw));
      half8_t a2 = *reinterpret_cast<const half8_t*>(rb + ((2 * 64 + kg * 16) ^ rsw));
      half8_t a3 = *reinterpret_cast<const half8_t*>(rb + ((3 * 64 + kg * 16) ^ rsw));

      f32x4_t C0 = {wxp[u][0][0], wxp[u][0][1], wxp[u][0][2], wxp[u][0][3]};
      f32x4_t C1 = {wxp[u][1][0], wxp[u][1][1], wxp[u][1][2], wxp[u][1][3]};
      C0 = __builtin_amdgcn_mfma_f32_16x16x32_f16(a0, Bf[0][0], C0, 0, 0, 0);
      C1 = __builtin_amdgcn_mfma_f32_16x16x32_f16(a0, Bf[1][0], C1, 0, 0, 0);
      C0 = __builtin_amdgcn_mfma_f32_16x16x32_f16(a1, Bf[0][1], C0, 0, 0, 0);
      C1 = __builtin_amdgcn_mfma_f32_16x16x32_f16(a1, Bf[1][1], C1, 0, 0, 0);
      C0 = __builtin_amdgcn_mfma_f32_16x16x32_f16(a2, Bf[0][2], C0, 0, 0, 0);
      C1 = __builtin_amdgcn_mfma_f32_16x16x32_f16(a2, Bf[1][2], C1, 0, 0, 0);
      C0 = __builtin_amdgcn_mfma_f32_16x16x32_f16(a3, Bf[0][3], C0, 0, 0, 0);
      C1 = __builtin_amdgcn_mfma_f32_16x16x32_f16(a3, Bf[1][3], C1, 0, 0, 0);

      char* wb = ybase_w + (cur ^ 1) * 4096;
#pragma unroll
      for (int j = 0; j < 4; ++j) {
        const int row = kg * 4 + j;     // batch row (C layout: row=(kg)*4+j)
        const int wsw = (row & 7) << 4;
        const float y0 = sigmoid2_fast(C0[j]);
        const float y1 = sigmoid2_fast(C1[j]);
        *reinterpret_cast<_Float16*>(wb + row * 256 + ((col0 * 2) ^ wsw)) = (_Float16)y0;
        *reinterpret_cast<_Float16*>(wb + row * 256 + ((col1 * 2) ^ wsw)) = (_Float16)y1;
        outb[((size_t)row * T_LEN + t) * H_DIM + col0] = y0;  // fire-and-forget
        outb[((size_t)row * T_LEN + t) * H_DIM + col1] = y1;
      }
      // publish@t before reads@t+1: this wave's DS ops committed, all waves
      // rendezvous. Global loads/stores stay in flight.
      asm volatile("s_waitcnt lgkmcnt(0)\n\ts_barrier" ::: "memory");
    }

    if (more) {
#pragma unroll
      for (int u = 0; u < RWND; ++u)
#pragma unroll
        for (int nt = 0; nt < 2; ++nt)
#pragma unroll
          for (int j = 0; j < 4; ++j)
            wxp[u][nt][j] = fmaf(wxn[u][nt][j], scl[nt], shf[nt]);
    }
  }
}

// ---------------------------------------------------------------------------
extern "C" void kernel_launch(void* const* d_in, const int* in_sizes, int n_in,
                              void* d_out, int out_size, void* d_ws, size_t ws_size,
                              hipStream_t stream)
{
  (void)in_sizes; (void)n_in; (void)out_size; (void)ws_size;
  const float* x     = (const float*)d_in[0];
  const float* W     = (const float*)d_in[1];
  const float* V     = (const float*)d_in[2];
  const float* gamma = (const float*)d_in[3];
  const float* beta  = (const float*)d_in[4];
  float* out = (float*)d_out;
  float* ws  = (float*)d_ws;

  hipMemsetAsync(ws, 0, 2 * H_DIM * sizeof(float), stream);
  gemm_bn_kernel<<<GEMM_GRID, 256, 0, stream>>>(x, W, out, ws);
  bn_finalize_kernel<<<1, H_DIM, 0, stream>>>(ws, gamma, beta);
  rnn_mfma_kernel<<<RNN_BLOCKS, 256, 0, stream>>>(V, out, ws);
}

// Round 13
// 516.977 us; speedup vs baseline: 1.7985x; 1.7985x over previous
//
#include <hip/hip_runtime.h>
#include <cstdint>
#include <cstddef>

#define N_ROWS 131072   // B*T
#define T_LEN 2048
#define B_BATCH 64
#define H_DIM 128
#define GEMM_GRID 1024  // 128 rows per block
#define WND 8           // rnn window (prefetch depth)
#define LOG2E 1.4426950408889634f

typedef _Float16 half2_t __attribute__((ext_vector_type(2)));
typedef _Float16 half8_t __attribute__((ext_vector_type(8)));
typedef float f32x4_t __attribute__((ext_vector_type(4)));
typedef int int2_t __attribute__((ext_vector_type(2)));

// DPP cross-lane ops (VALU pipe, no LDS) — rnn reduce-scatter.
__device__ __forceinline__ float dpp_xor1(float x) {
  int i = __float_as_int(x);
  return __int_as_float(__builtin_amdgcn_update_dpp(i, i, 0xB1, 0xF, 0xF, true));
}
__device__ __forceinline__ float dpp_xor2(float x) {
  int i = __float_as_int(x);
  return __int_as_float(__builtin_amdgcn_update_dpp(i, i, 0x4E, 0xF, 0xF, true));
}
__device__ __forceinline__ float dpp_mirror8(float x) {
  int i = __float_as_int(x);
  return __int_as_float(__builtin_amdgcn_update_dpp(i, i, 0x141, 0xF, 0xF, true));
}

// permlaneN_swap butterfly sum: lane i ends with x[i] + x[i^N].
__device__ __forceinline__ float permlane16_sum(float x) {
  int i = __float_as_int(x);
  int2_t r = __builtin_amdgcn_permlane16_swap(i, i, false, false);
  return __int_as_float(r.x) + __int_as_float(r.y);
}
__device__ __forceinline__ float permlane32_sum(float x) {
  int i = __float_as_int(x);
  int2_t r = __builtin_amdgcn_permlane32_swap(i, i, false, false);
  return __int_as_float(r.x) + __int_as_float(r.y);
}

__device__ __forceinline__ float sigmoid2_fast(float spp) {
  // y = 1/(1 + 2^spp), spp already scaled by -log2e
  return __builtin_amdgcn_rcpf(1.0f + __builtin_amdgcn_exp2f(spp));
}

// ---------------------------------------------------------------------------
// Kernel 1: Wx = x @ W^T + fused BN column stats — MFMA (R10/R11-verified).
// 128x128 tile/block; 4 waves x 2 n-tiles; x staged to LDS as f16 with XOR
// swizzle (byte ^= (row&7)<<4); A/B/C fragment layouts HW-verified.
// ---------------------------------------------------------------------------
__global__ __launch_bounds__(256) void gemm_bn_kernel(
    const float* __restrict__ x, const float* __restrict__ W,
    float* __restrict__ Wx, float* __restrict__ stats)
{
  const int tid  = threadIdx.x;
  const int lane = tid & 63;
  const int wv   = tid >> 6;        // wave 0..3
  const int l15  = lane & 15;
  const int kg   = lane >> 4;       // k-group 0..3
  const int r0   = blockIdx.x * 128;

  half8_t Bf[2][4];
#pragma unroll
  for (int n = 0; n < 2; ++n) {
    const int col = wv * 32 + n * 16 + l15;
    const float* wp = W + (size_t)col * H_DIM;
#pragma unroll
    for (int k = 0; k < 4; ++k) {
      const float* w8 = wp + k * 32 + kg * 8;
      half8_t b;
#pragma unroll
      for (int i = 0; i < 8; ++i) b[i] = (_Float16)w8[i];
      Bf[n][k] = b;
    }
  }

  __shared__ __align__(16) _Float16 xs[128 * 128];
  {
    const int row = tid >> 1;
    const int hf  = tid & 1;
    const float* xp = x + (size_t)(r0 + row) * H_DIM + hf * 64;
    const int swz = (row & 7) << 4;
    char* base = reinterpret_cast<char*>(xs) + row * 256;
#pragma unroll
    for (int c = 0; c < 8; ++c) {
      float4 v0 = *reinterpret_cast<const float4*>(xp + c * 8);
      float4 v1 = *reinterpret_cast<const float4*>(xp + c * 8 + 4);
      half8_t h;
      h[0] = (_Float16)v0.x; h[1] = (_Float16)v0.y;
      h[2] = (_Float16)v0.z; h[3] = (_Float16)v0.w;
      h[4] = (_Float16)v1.x; h[5] = (_Float16)v1.y;
      h[6] = (_Float16)v1.z; h[7] = (_Float16)v1.w;
      const int X = hf * 128 + c * 16;
      *reinterpret_cast<half8_t*>(base + (X ^ swz)) = h;
    }
  }
  __syncthreads();

  f32x4_t C[8][2];
#pragma unroll
  for (int m = 0; m < 8; ++m)
#pragma unroll
    for (int n = 0; n < 2; ++n)
      C[m][n] = (f32x4_t){0.f, 0.f, 0.f, 0.f};

#pragma unroll
  for (int m = 0; m < 8; ++m) {
    const int row = m * 16 + l15;
    const char* rbase = reinterpret_cast<const char*>(xs) + row * 256;
    const int swz = (row & 7) << 4;
#pragma unroll
    for (int k = 0; k < 4; ++k) {
      const int X = k * 64 + kg * 16;
      half8_t a = *reinterpret_cast<const half8_t*>(rbase + (X ^ swz));
      C[m][0] = __builtin_amdgcn_mfma_f32_16x16x32_f16(a, Bf[0][k], C[m][0], 0, 0, 0);
      C[m][1] = __builtin_amdgcn_mfma_f32_16x16x32_f16(a, Bf[1][k], C[m][1], 0, 0, 0);
    }
  }

  float sum0 = 0.f, sq0 = 0.f, sum1 = 0.f, sq1 = 0.f;
#pragma unroll
  for (int m = 0; m < 8; ++m) {
#pragma unroll
    for (int j = 0; j < 4; ++j) {
      const int row = r0 + m * 16 + kg * 4 + j;
      const float v0 = C[m][0][j];
      const float v1 = C[m][1][j];
      Wx[(size_t)row * H_DIM + wv * 32 + l15]      = v0;
      Wx[(size_t)row * H_DIM + wv * 32 + 16 + l15] = v1;
      sum0 += v0; sq0 = fmaf(v0, v0, sq0);
      sum1 += v1; sq1 = fmaf(v1, v1, sq1);
    }
  }
  float s0 = permlane32_sum(permlane16_sum(sum0));
  float q0 = permlane32_sum(permlane16_sum(sq0));
  float s1 = permlane32_sum(permlane16_sum(sum1));
  float q1 = permlane32_sum(permlane16_sum(sq1));
  if (lane < 16) {
    atomicAdd(&stats[wv * 32 + lane],              s0);
    atomicAdd(&stats[H_DIM + wv * 32 + lane],      q0);
    atomicAdd(&stats[wv * 32 + 16 + lane],         s1);
    atomicAdd(&stats[H_DIM + wv * 32 + 16 + lane], q1);
  }
}

// ---------------------------------------------------------------------------
// Kernel 2: recurrence — proven 4-wave fdot2 design (471 us; best of four
// measured structures: 16w 1412 / 4w 552 / 1w 923 / 4w-MFMA 1042 cyc/step).
// BN finalize fused into prologue (saves one launch): each thread derives
// scale/shift from raw stats + gamma/beta.
// ---------------------------------------------------------------------------
__global__ __launch_bounds__(256) void rnn_kernel(
    const float* __restrict__ V, float* __restrict__ out,
    const float* __restrict__ ws, const float* __restrict__ gamma,
    const float* __restrict__ beta)
{
  const int tid = threadIdx.x;
  const int hq = tid >> 3;           // 0..31
  const int l7 = tid & 7;            // lane within 8-group
  const int g  = (l7 & 3) ^ (3 * ((l7 >> 2) & 1));
  const int h_own = hq + (g << 5);
  const bool wr = (tid & 4) == 0;    // lanes l7<4: unique row owners/writers

  half2_t Vh[4][8];
#pragma unroll
  for (int j = 0; j < 4; ++j) {
    const int hrow = hq + (((unsigned)(j ^ g)) << 5);
    const float* vp = V + (size_t)hrow * H_DIM + (l7 << 4);
#pragma unroll
    for (int i = 0; i < 8; ++i) {
      half2_t h;
      h.x = (_Float16)(-LOG2E * vp[2 * i]);
      h.y = (_Float16)(-LOG2E * vp[2 * i + 1]);
      Vh[j][i] = h;
    }
  }
  // fused BN finalize: scale/shift from raw column stats
  float scl2, shf2;
  {
    const float invN = 1.0f / (float)N_ROWS;
    const float mean = ws[h_own] * invN;
    const float var  = ws[H_DIM + h_own] * invN - mean * mean;
    const float scl  = gamma[h_own] * rsqrtf(var + 1e-5f);
    const float shf  = beta[h_own] - mean * scl;
    scl2 = scl * (-LOG2E);
    shf2 = shf * (-LOG2E);
  }

  __shared__ __align__(16) _Float16 ylds[2][H_DIM];

  float* outb = out + (size_t)blockIdx.x * T_LEN * H_DIM;

  if (tid < H_DIM) { ylds[0][tid] = (_Float16)0.f; ylds[1][tid] = (_Float16)0.f; }

  float wxp[WND];
  if (wr) {
#pragma unroll
    for (int u = 0; u < WND; ++u)
      wxp[u] = fmaf(outb[(size_t)u * H_DIM + h_own], scl2, shf2);
  } else {
#pragma unroll
    for (int u = 0; u < WND; ++u) wxp[u] = 0.f;
  }
  __syncthreads();

  float yreg[WND];

  for (int w = 0; w < T_LEN; w += WND) {
    const bool more = (w + WND < T_LEN);
    float wxn[WND];
    if (more && wr) {  // prefetch next window's wx (hides under 8 steps)
#pragma unroll
      for (int u = 0; u < WND; ++u)
        wxn[u] = outb[(size_t)(w + WND + u) * H_DIM + h_own];
    } else {
#pragma unroll
      for (int u = 0; u < WND; ++u) wxn[u] = 0.f;
    }

#pragma unroll
    for (int u = 0; u < WND; ++u) {
      const int t = w + u;
      const uint4* yv = reinterpret_cast<const uint4*>(&ylds[t & 1][l7 << 4]);
      uint4 w0 = yv[0], w1 = yv[1];
      half2_t y2[8];
      y2[0] = __builtin_bit_cast(half2_t, w0.x);
      y2[1] = __builtin_bit_cast(half2_t, w0.y);
      y2[2] = __builtin_bit_cast(half2_t, w0.z);
      y2[3] = __builtin_bit_cast(half2_t, w0.w);
      y2[4] = __builtin_bit_cast(half2_t, w1.x);
      y2[5] = __builtin_bit_cast(half2_t, w1.y);
      y2[6] = __builtin_bit_cast(half2_t, w1.z);
      y2[7] = __builtin_bit_cast(half2_t, w1.w);

      float a0 = 0.f, a1 = 0.f, a2 = 0.f, a3 = 0.f;
#pragma unroll
      for (int i = 0; i < 8; ++i) {
        a0 = __builtin_amdgcn_fdot2(y2[i], Vh[0][i], a0, false);
        a1 = __builtin_amdgcn_fdot2(y2[i], Vh[1][i], a1, false);
        a2 = __builtin_amdgcn_fdot2(y2[i], Vh[2][i], a2, false);
        a3 = __builtin_amdgcn_fdot2(y2[i], Vh[3][i], a3, false);
      }
      float b0 = a0 + dpp_xor1(a1);
      float b1 = a2 + dpp_xor1(a3);
      float c  = b0 + dpp_xor2(b1);
      float red = c + dpp_mirror8(c);
      const float spp = red + wxp[u];
      const float y = sigmoid2_fast(spp);
      if (wr) ylds[(t & 1) ^ 1][h_own] = (_Float16)y;
      yreg[u] = y;
      // LDS visibility only; global loads/stores stay in flight.
      asm volatile("s_waitcnt lgkmcnt(0)\n\ts_barrier" ::: "memory");
    }

    if (wr) {  // flush window outputs (overwrites consumed Wx)
#pragma unroll
      for (int u = 0; u < WND; ++u)
        outb[(size_t)(w + u) * H_DIM + h_own] = yreg[u];
    }
#pragma unroll
    for (int u = 0; u < WND; ++u) wxp[u] = fmaf(wxn[u], scl2, shf2);
  }
}

// ---------------------------------------------------------------------------
extern "C" void kernel_launch(void* const* d_in, const int* in_sizes, int n_in,
                              void* d_out, int out_size, void* d_ws, size_t ws_size,
                              hipStream_t stream)
{
  (void)in_sizes; (void)n_in; (void)out_size; (void)ws_size;
  const float* x     = (const float*)d_in[0];
  const float* W     = (const float*)d_in[1];
  const float* V     = (const float*)d_in[2];
  const float* gamma = (const float*)d_in[3];
  const float* beta  = (const float*)d_in[4];
  float* out = (float*)d_out;
  float* ws  = (float*)d_ws;

  hipMemsetAsync(ws, 0, 2 * H_DIM * sizeof(float), stream);
  gemm_bn_kernel<<<GEMM_GRID, 256, 0, stream>>>(x, W, out, ws);
  rnn_kernel<<<B_BATCH, 256, 0, stream>>>(V, out, ws, gamma, beta);
}